// Round 5
// baseline (626.652 us; speedup 1.0000x reference)
//
#include <hip/hip_runtime.h>
#include <hip/hip_bf16.h>

#define N_ATOMS 32768
#define N_EDGESC 262144
#define ATOM_F 256
#define EDGE_F 128
#define OUT_F 512
#define N_GAUSS 50
#define IN_F 690
#define NCHUNK 11

#define BM 64
#define BN 256
#define NTHREADS 256

using f32x4  = __attribute__((ext_vector_type(4))) float;
using short8 = __attribute__((ext_vector_type(8))) short;

__device__ __forceinline__ unsigned short f2bf(float f) {
  unsigned int u = __builtin_bit_cast(unsigned int, f);
  u += 0x7fffu + ((u >> 16) & 1u);   // round-to-nearest-even
  return (unsigned short)(u >> 16);
}

// packed f32x2 -> bf16x2 via v_cvt_pk_bf16_f32 (memcpy: __hip_bfloat162 is
// not trivially copyable so bit_cast is rejected; memcpy lowers to a mov)
__device__ __forceinline__ unsigned int pack_bf2(float a, float b) {
  __hip_bfloat162 t = __float22bfloat162_rn(float2{a, b});
  unsigned int u;
  __builtin_memcpy(&u, &t, 4);
  return u;
}

// ---- detect int64 vs int32 edge_index (deterministic, data-driven) ----
__global__ void detect_idx_kernel(const unsigned int* __restrict__ ei, int* __restrict__ flag) {
  if (threadIdx.x == 0) {
    int ok = 1;
    for (int i = 0; i < 64; ++i) {
      unsigned int lo = ei[2 * i], hi = ei[2 * i + 1];
      if (hi != 0u || lo >= (unsigned)N_ATOMS) { ok = 0; break; }
    }
    *flag = ok;  // 1 => int64 layout
  }
}

// ---- W (512x690 fp32 [n][k]) -> Wp bf16 in MFMA-fragment order ----
// Fragment (kc, ks, nt): 64 lanes x 16B contiguous (1 KB).
// lane l holds B[n = nt*16 + (l&15)][k = kc*64 + ks*32 + (l>>4)*8 + j], j=0..7
__global__ void prep_w_kernel(const float* __restrict__ W, unsigned short* __restrict__ Wp) {
  int g = blockIdx.x * blockDim.x + threadIdx.x;   // one thread per fragment-lane
  if (g >= NCHUNK * 2 * 32 * 64) return;
  int l  = g & 63;
  int nt = (g >> 6) & 31;
  int ks = (g >> 11) & 1;
  int kc = g >> 12;
  int n  = nt * 16 + (l & 15);
  int k0 = kc * 64 + ks * 32 + ((l >> 4) << 3);
  unsigned int u[4];
#pragma unroll
  for (int p = 0; p < 4; ++p) {
    int ka = k0 + 2 * p, kb = k0 + 2 * p + 1;
    float va = (ka < IN_F) ? W[n * IN_F + ka] : 0.0f;
    float vb = (kb < IN_F) ? W[n * IN_F + kb] : 0.0f;
    u[p] = (unsigned)f2bf(va) | ((unsigned)f2bf(vb) << 16);
  }
  *(uint4*)(Wp + (size_t)g * 8) = make_uint4(u[0], u[1], u[2], u[3]);
}

// ---- fused gather + gaussian + GEMM ----
// BM=64 edges x BN=256 cols; 4 waves (wave tile 64x64); target 4 blocks/CU.
// Depth-2 register prefetch: load(k+2) issued at chunk k, LDS-written at k+1.
__global__ __launch_bounds__(NTHREADS, 4) void gemm_kernel(
    const float* __restrict__ h, const float* __restrict__ m,
    const float* __restrict__ magft, const void* __restrict__ ei,
    const int* __restrict__ flagp, const unsigned short* __restrict__ Wp,
    float* __restrict__ out)
{
  __shared__ __align__(16) unsigned short As[2][BM * 64];  // 2 x 8 KB, XOR-swizzled
  __shared__ int sIdx[BM], tIdx[BM];
  __shared__ float dLDS[BM];

  const int tid = threadIdx.x;
  const int eb  = blockIdx.x * BM;     // edge block (x fastest -> n-pair lands same XCD)
  const int ntb = blockIdx.y * 16;     // base n-tile (16 cols each)

  const int use64 = *flagp;
  if (tid < BM) {
    int e = eb + tid;
    int s, tg;
    if (use64) {
      const long long* p = (const long long*)ei;
      s  = (int)p[e];
      tg = (int)p[N_EDGESC + e];
    } else {
      const int* p = (const int*)ei;
      s  = p[e];
      tg = p[N_EDGESC + e];
    }
    sIdx[tid] = s;
    tIdx[tid] = tg;
    float ax = magft[3 * s],  ay = magft[3 * s + 1],  az = magft[3 * s + 2];
    float bx = magft[3 * tg], by = magft[3 * tg + 1], bz = magft[3 * tg + 2];
    dLDS[tid] = ax * bx + ay * by + az * bz;
  }
  __syncthreads();

  const int lane = tid & 63;
  const int wc   = tid >> 6;     // wave 0..3 -> N quarter (64 cols)

  const int ar = tid >> 2;       // staging row 0..63
  const int aq = tid & 3;        // staging quarter (16 fp32 cols)

  // ---- issue gathers (or compute gaussians) into a register buffer ----
  auto stage_load = [&](int kchunk, float4 (&vb)[4]) {
    if (kchunk < 10) {
      const float* p;
      if (kchunk < 8) {
        int atom = (kchunk < 4) ? sIdx[ar] : tIdx[ar];
        p = h + (size_t)atom * ATOM_F + (kchunk & 3) * 64 + aq * 16;
      } else {
        p = m + (size_t)(eb + ar) * EDGE_F + (kchunk & 1) * 64 + aq * 16;
      }
#pragma unroll
      for (int j = 0; j < 4; ++j) vb[j] = ((const float4*)p)[j];
    } else {
      float d = dLDS[ar];
      const float step  = 3.0f / 49.0f;
      const float coeff = -0.5f / (step * step);
#pragma unroll
      for (int j = 0; j < 4; ++j) {
#pragma unroll
        for (int t = 0; t < 4; ++t) {
          int c = aq * 16 + j * 4 + t;
          float o = -1.5f + step * (float)c;
          vb[j][t] = (c < N_GAUSS) ? __expf(coeff * (d - o) * (d - o)) : 0.0f;
        }
      }
    }
  };

  // ---- packed cvt + swizzled ds_write ----
  auto stage_write = [&](int buf, float4 (&vb)[4]) {
    unsigned int u[8];
#pragma unroll
    for (int j = 0; j < 4; ++j) {
      u[2 * j]     = pack_bf2(vb[j].x, vb[j].y);
      u[2 * j + 1] = pack_bf2(vb[j].z, vb[j].w);
    }
    char* base = (char*)&As[buf][0] + ar * 128;
    const int sw = (ar & 7) << 4;
    *(uint4*)(base + ((aq * 32)      ^ sw)) = make_uint4(u[0], u[1], u[2], u[3]);
    *(uint4*)(base + ((aq * 32 + 16) ^ sw)) = make_uint4(u[4], u[5], u[6], u[7]);
  };

  f32x4 acc[4][4];
#pragma unroll
  for (int i = 0; i < 4; ++i)
#pragma unroll
    for (int j = 0; j < 4; ++j) acc[i][j] = (f32x4){0.f, 0.f, 0.f, 0.f};

  const short8* Wp8 = (const short8*)Wp;

  auto compute = [&](int kc) {
    const char* abase = (const char*)&As[kc & 1][0];
#pragma unroll
    for (int ks = 0; ks < 2; ++ks) {
      short8 b[4];
#pragma unroll
      for (int ni = 0; ni < 4; ++ni)
        b[ni] = Wp8[(size_t)(((kc * 2 + ks) * 32 + ntb + wc * 4 + ni) << 6) + lane];
      short8 a[4];
#pragma unroll
      for (int mi = 0; mi < 4; ++mi) {
        int row = mi * 16 + (lane & 15);
        int colb = (ks * 64 + ((lane >> 4) << 4)) ^ ((row & 7) << 4);
        a[mi] = *(const short8*)(abase + row * 128 + colb);
      }
      __builtin_amdgcn_s_setprio(1);
#pragma unroll
      for (int mi = 0; mi < 4; ++mi)
#pragma unroll
        for (int ni = 0; ni < 4; ++ni)
          acc[mi][ni] = __builtin_amdgcn_mfma_f32_16x16x32_bf16(a[mi], b[ni], acc[mi][ni], 0, 0, 0);
      __builtin_amdgcn_s_setprio(0);
    }
  };

  float4 vA[4], vB[4];

  // prologue: chunk0 staged (stall once), chunk1 load in flight
  stage_load(0, vA);
  stage_write(0, vA);
  stage_load(1, vB);
  __syncthreads();

  // main loop, manually 2-unrolled so vA/vB stay statically indexed
  for (int kc2 = 0; kc2 < NCHUNK; kc2 += 2) {
    {   // chunk kc2 (even): incoming load -> vA, pending write from vB
      if (kc2 + 2 < NCHUNK) stage_load(kc2 + 2, vA);
      compute(kc2);
      if (kc2 + 1 < NCHUNK) {
        stage_write((kc2 + 1) & 1, vB);
        __syncthreads();
      }
    }
    if (kc2 + 1 < NCHUNK) {  // chunk kc2+1 (odd): load -> vB, write from vA
      int kc = kc2 + 1;
      if (kc + 2 < NCHUNK) stage_load(kc + 2, vB);
      compute(kc);
      if (kc + 1 < NCHUNK) {
        stage_write((kc + 1) & 1, vA);
        __syncthreads();
      }
    }
  }

  // ---- epilogue: C/D layout col=lane&15, row=(lane>>4)*4+j ----
#pragma unroll
  for (int mi = 0; mi < 4; ++mi) {
    int row0 = eb + mi * 16 + ((lane >> 4) << 2);
#pragma unroll
    for (int ni = 0; ni < 4; ++ni) {
      int col = ntb * 16 + wc * 64 + ni * 16 + (lane & 15);
#pragma unroll
      for (int j = 0; j < 4; ++j) {
        out[(size_t)(row0 + j) * OUT_F + col] = acc[mi][ni][j];
      }
    }
  }
}

extern "C" void kernel_launch(void* const* d_in, const int* in_sizes, int n_in,
                              void* d_out, int out_size, void* d_ws, size_t ws_size,
                              hipStream_t stream) {
  const float* h     = (const float*)d_in[0];
  const float* m     = (const float*)d_in[1];
  const float* magft = (const float*)d_in[2];
  const void*  ei    = d_in[3];
  const float* W     = (const float*)d_in[4];
  float* out = (float*)d_out;

  char* ws = (char*)d_ws;
  int* flag = (int*)ws;
  unsigned short* Wp = (unsigned short*)(ws + 256);  // 704 KB fragment-packed W

  detect_idx_kernel<<<1, 64, 0, stream>>>((const unsigned int*)ei, flag);
  prep_w_kernel<<<(NCHUNK * 2 * 32 * 64 + 255) / 256, 256, 0, stream>>>(W, Wp);

  gemm_kernel<<<dim3(N_EDGESC / BM, OUT_F / BN), NTHREADS, 0, stream>>>(h, m, magft, ei, flag, Wp, out);
}

// Round 6
// 328.269 us; speedup vs baseline: 1.9090x; 1.9090x over previous
//
#include <hip/hip_runtime.h>
#include <hip/hip_bf16.h>

#define N_ATOMS 32768
#define N_EDGESC 262144
#define ATOM_F 256
#define EDGE_F 128
#define OUT_F 512
#define N_GAUSS 50
#define IN_F 690
#define NCHUNK 11

#define BM 128
#define BN 256
#define NTHREADS 512

using f32x4  = __attribute__((ext_vector_type(4))) float;
using short8 = __attribute__((ext_vector_type(8))) short;

__device__ __forceinline__ unsigned short f2bf(float f) {
  unsigned int u = __builtin_bit_cast(unsigned int, f);
  u += 0x7fffu + ((u >> 16) & 1u);   // round-to-nearest-even
  return (unsigned short)(u >> 16);
}

// ---- detect int64 vs int32 edge_index (deterministic, data-driven) ----
__global__ void detect_idx_kernel(const unsigned int* __restrict__ ei, int* __restrict__ flag) {
  if (threadIdx.x == 0) {
    int ok = 1;
    for (int i = 0; i < 64; ++i) {
      unsigned int lo = ei[2 * i], hi = ei[2 * i + 1];
      if (hi != 0u || lo >= (unsigned)N_ATOMS) { ok = 0; break; }
    }
    *flag = ok;  // 1 => int64 layout
  }
}

// ---- h (32768x256 f32) -> hb (bf16, row-major) ----
__global__ void prep_h_kernel(const float* __restrict__ h, unsigned short* __restrict__ hb) {
  size_t i = (size_t)(blockIdx.x * blockDim.x + threadIdx.x) * 8;  // 8 elems/thread
  if (i >= (size_t)N_ATOMS * ATOM_F) return;
  float4 a = *(const float4*)(h + i);
  float4 b = *(const float4*)(h + i + 4);
  uint4 o;
  o.x = (unsigned)f2bf(a.x) | ((unsigned)f2bf(a.y) << 16);
  o.y = (unsigned)f2bf(a.z) | ((unsigned)f2bf(a.w) << 16);
  o.z = (unsigned)f2bf(b.x) | ((unsigned)f2bf(b.y) << 16);
  o.w = (unsigned)f2bf(b.z) | ((unsigned)f2bf(b.w) << 16);
  *(uint4*)(hb + i) = o;
}

// ---- W (512x690 fp32 [n][k]) -> Wp bf16 in MFMA-fragment order ----
// Fragment (kc, ks, nt): 64 lanes x 16B contiguous (1 KB).
// lane l holds B[n = nt*16 + (l&15)][k = kc*64 + ks*32 + (l>>4)*8 + j], j=0..7
__global__ void prep_w_kernel(const float* __restrict__ W, unsigned short* __restrict__ Wp) {
  int g = blockIdx.x * blockDim.x + threadIdx.x;
  if (g >= NCHUNK * 2 * 32 * 64) return;
  int l  = g & 63;
  int nt = (g >> 6) & 31;
  int ks = (g >> 11) & 1;
  int kc = g >> 12;
  int n  = nt * 16 + (l & 15);
  int k0 = kc * 64 + ks * 32 + ((l >> 4) << 3);
  unsigned int u[4];
#pragma unroll
  for (int p = 0; p < 4; ++p) {
    int ka = k0 + 2 * p, kb = k0 + 2 * p + 1;
    float va = (ka < IN_F) ? W[n * IN_F + ka] : 0.0f;
    float vb = (kb < IN_F) ? W[n * IN_F + kb] : 0.0f;
    u[p] = (unsigned)f2bf(va) | ((unsigned)f2bf(vb) << 16);
  }
  *(uint4*)(Wp + (size_t)g * 8) = make_uint4(u[0], u[1], u[2], u[3]);
}

// ---- fused gather + gaussian + GEMM ----
// BM=128 x BN=256; 8 waves (2M x 4N, wave tile 64x64); 2 blocks/CU.
// h-chunks staged via global_load_lds (pre-swizzled source, linear LDS dest);
// m/gauss chunks via reg->cvt->swizzled ds_write. 3-buffer rotation, depth-2.
__global__ __launch_bounds__(NTHREADS, 4) void gemm_kernel(
    const unsigned short* __restrict__ hb, const float* __restrict__ m,
    const float* __restrict__ magft, const void* __restrict__ ei,
    const int* __restrict__ flagp, const unsigned short* __restrict__ Wp,
    float* __restrict__ out)
{
  __shared__ __align__(16) unsigned short As[3][BM * 64];  // 3 x 16 KB
  __shared__ int sIdx[BM], tIdx[BM];
  __shared__ float dLDS[BM];

  const int tid = threadIdx.x;
  const int bid = blockIdx.x;
  // decode so the two n-halves of an edge-block are 8 dispatches apart (same XCD)
  const int e  = (bid & 7) | ((bid >> 4) << 3);
  const int nh = (bid >> 3) & 1;
  const int eb = e * BM;

  const int use64 = *flagp;
  if (tid < BM) {
    int ed = eb + tid;
    int s, tg;
    if (use64) {
      const long long* p = (const long long*)ei;
      s  = (int)p[ed];
      tg = (int)p[N_EDGESC + ed];
    } else {
      const int* p = (const int*)ei;
      s  = p[ed];
      tg = p[N_EDGESC + ed];
    }
    sIdx[tid] = s;
    tIdx[tid] = tg;
    float ax = magft[3 * s],  ay = magft[3 * s + 1],  az = magft[3 * s + 2];
    float bx = magft[3 * tg], by = magft[3 * tg + 1], bz = magft[3 * tg + 2];
    dLDS[tid] = ax * bx + ay * by + az * bz;
  }
  __syncthreads();

  const int lane = tid & 63;
  const int wid  = tid >> 6;     // 0..7
  const int wr   = wid >> 2;     // M half
  const int wc   = wid & 3;      // N quarter

  // glds geometry: wave wid covers rows [wid*16, wid*16+16), 2 instrs x 1KB.
  // lane l, instr j -> row = wid*16 + j*8 + (l>>3), seg = l&7 (16B col chunk).
  const int r0 = wid * 16 + (lane >> 3);       // row for j=0 (j=1 is r0+8)
  const int hs0 = sIdx[r0], hs1 = sIdx[r0 + 8];
  const int ht0 = tIdx[r0], ht1 = tIdx[r0 + 8];
  // pre-swizzled source byte offset within the 128B row-slice:
  const int srcsw = (((lane & 7) ^ (lane >> 3)) << 4);

  const int ar = tid >> 2;       // tid-path staging row 0..127
  const int aq = tid & 3;        // 16-f32 quarter

  auto stage = [&](int kchunk, int buf) {
    if (kchunk < 8) {
      // ---- h gather via global_load_lds, bf16 source, swizzled src addr ----
      int a0 = (kchunk < 4) ? hs0 : ht0;
      int a1 = (kchunk < 4) ? hs1 : ht1;
      const char* s0 = (const char*)hb + ((size_t)a0 * ATOM_F + (kchunk & 3) * 64) * 2 + srcsw;
      const char* s1 = (const char*)hb + ((size_t)a1 * ATOM_F + (kchunk & 3) * 64) * 2 + srcsw;
      char* d0 = (char*)&As[buf][0] + wid * 2048;
      __builtin_amdgcn_global_load_lds(
          (const __attribute__((address_space(1))) void*)s0,
          (__attribute__((address_space(3))) void*)d0, 16, 0, 0);
      __builtin_amdgcn_global_load_lds(
          (const __attribute__((address_space(1))) void*)s1,
          (__attribute__((address_space(3))) void*)(d0 + 1024), 16, 0, 0);
    } else {
      unsigned int u[8];
      if (kchunk < 10) {
        const float* p = m + (size_t)(eb + ar) * EDGE_F + (kchunk & 1) * 64 + aq * 16;
        float4 v0 = ((const float4*)p)[0], v1 = ((const float4*)p)[1];
        float4 v2 = ((const float4*)p)[2], v3 = ((const float4*)p)[3];
        u[0] = (unsigned)f2bf(v0.x) | ((unsigned)f2bf(v0.y) << 16);
        u[1] = (unsigned)f2bf(v0.z) | ((unsigned)f2bf(v0.w) << 16);
        u[2] = (unsigned)f2bf(v1.x) | ((unsigned)f2bf(v1.y) << 16);
        u[3] = (unsigned)f2bf(v1.z) | ((unsigned)f2bf(v1.w) << 16);
        u[4] = (unsigned)f2bf(v2.x) | ((unsigned)f2bf(v2.y) << 16);
        u[5] = (unsigned)f2bf(v2.z) | ((unsigned)f2bf(v2.w) << 16);
        u[6] = (unsigned)f2bf(v3.x) | ((unsigned)f2bf(v3.y) << 16);
        u[7] = (unsigned)f2bf(v3.z) | ((unsigned)f2bf(v3.w) << 16);
      } else {
        float d = dLDS[ar];
        const float step  = 3.0f / 49.0f;
        const float coeff = -0.5f / (step * step);
#pragma unroll
        for (int p2 = 0; p2 < 8; ++p2) {
          int c0 = aq * 16 + 2 * p2, c1 = c0 + 1;
          float o0 = -1.5f + step * (float)c0;
          float o1 = -1.5f + step * (float)c1;
          float w0 = (c0 < N_GAUSS) ? __expf(coeff * (d - o0) * (d - o0)) : 0.0f;
          float w1 = (c1 < N_GAUSS) ? __expf(coeff * (d - o1) * (d - o1)) : 0.0f;
          u[p2] = (unsigned)f2bf(w0) | ((unsigned)f2bf(w1) << 16);
        }
      }
      char* base = (char*)&As[buf][0] + ar * 128;
      const int sw = (ar & 7) << 4;
      *(uint4*)(base + ((aq * 32)      ^ sw)) = make_uint4(u[0], u[1], u[2], u[3]);
      *(uint4*)(base + ((aq * 32 + 16) ^ sw)) = make_uint4(u[4], u[5], u[6], u[7]);
    }
  };

  f32x4 acc[4][4];
#pragma unroll
  for (int i = 0; i < 4; ++i)
#pragma unroll
    for (int j = 0; j < 4; ++j) acc[i][j] = (f32x4){0.f, 0.f, 0.f, 0.f};

  const short8* Wp8 = (const short8*)Wp;

  auto compute = [&](int kc, int buf) {
    const char* abase = (const char*)&As[buf][0];
#pragma unroll
    for (int ks = 0; ks < 2; ++ks) {
      short8 b[4];
#pragma unroll
      for (int ni = 0; ni < 4; ++ni) {
        int nt = nh * 16 + wc * 4 + ni;
        b[ni] = Wp8[(size_t)(((kc * 2 + ks) * 32 + nt) << 6) + lane];
      }
      short8 a[4];
#pragma unroll
      for (int mi = 0; mi < 4; ++mi) {
        int row = wr * 64 + mi * 16 + (lane & 15);
        int colb = (ks * 64 + ((lane >> 4) << 4)) ^ ((row & 7) << 4);
        a[mi] = *(const short8*)(abase + row * 128 + colb);
      }
      __builtin_amdgcn_s_setprio(1);
#pragma unroll
      for (int mi = 0; mi < 4; ++mi)
#pragma unroll
        for (int ni = 0; ni < 4; ++ni)
          acc[mi][ni] = __builtin_amdgcn_mfma_f32_16x16x32_bf16(a[mi], b[ni], acc[mi][ni], 0, 0, 0);
      __builtin_amdgcn_s_setprio(0);
    }
  };

  // prologue: chunks 0 and 1 staged/in-flight
  stage(0, 0);
  stage(1, 1);
  __syncthreads();

  // main loop: 3-buffer rotation, stage k+2 while computing k, 1 barrier/chunk
  for (int kc = 0; kc < NCHUNK; ++kc) {
    if (kc + 2 < NCHUNK) stage(kc + 2, (kc + 2) % 3);
    compute(kc, kc % 3);
    if (kc + 1 < NCHUNK) __syncthreads();
  }

  // ---- epilogue: C/D layout col=lane&15, row=(lane>>4)*4+j ----
#pragma unroll
  for (int mi = 0; mi < 4; ++mi) {
    int row0 = eb + wr * 64 + mi * 16 + ((lane >> 4) << 2);
#pragma unroll
    for (int ni = 0; ni < 4; ++ni) {
      int col = nh * 256 + wc * 64 + ni * 16 + (lane & 15);
#pragma unroll
      for (int j = 0; j < 4; ++j) {
        out[(size_t)(row0 + j) * OUT_F + col] = acc[mi][ni][j];
      }
    }
  }
}

extern "C" void kernel_launch(void* const* d_in, const int* in_sizes, int n_in,
                              void* d_out, int out_size, void* d_ws, size_t ws_size,
                              hipStream_t stream) {
  const float* h     = (const float*)d_in[0];
  const float* m     = (const float*)d_in[1];
  const float* magft = (const float*)d_in[2];
  const void*  ei    = d_in[3];
  const float* W     = (const float*)d_in[4];
  float* out = (float*)d_out;

  char* ws = (char*)d_ws;
  int* flag = (int*)ws;
  unsigned short* Wp = (unsigned short*)(ws + 256);            // 704 KB
  unsigned short* hb = (unsigned short*)(ws + 256 + 720896);   // 16 MB bf16 h

  detect_idx_kernel<<<1, 64, 0, stream>>>((const unsigned int*)ei, flag);
  prep_w_kernel<<<(NCHUNK * 2 * 32 * 64 + 255) / 256, 256, 0, stream>>>(W, Wp);
  prep_h_kernel<<<(N_ATOMS * ATOM_F / 8 + 255) / 256, 256, 0, stream>>>(h, hb);

  gemm_kernel<<<dim3(2 * N_EDGESC / BM), NTHREADS, 0, stream>>>(hb, m, magft, ei, flag, Wp, out);
}